// Round 3
// baseline (1640.844 us; speedup 1.0000x reference)
//
#include <hip/hip_runtime.h>
#include <math.h>

#define NAGENT 10
#define OBS_D  64
#define HID    50
#define NSYM   10
#define NACT   2
#define NEGV   (-1e9f)

#define BPB 6                // batch elements per block
#define TPB 64               // one wave
#define AG  (BPB * NAGENT)   // 60 active lanes

#define LD  52               // padded weight row stride (16B-aligned rows)
#define CLD 12               // padded W_comm row stride (48B rows, 16B-aligned)

// ws layout (floats):
//  WencP [64][52] @ 0      : W_enc rows
//  WC0   [50][52] @ 3328   : W_f0[h] + W_f0[skip] rows (both multiply h0 at step 0)
//  W1S   [50][52] @ 5928   : W_f1[skip] rows
//  W1H   [50][52] @ 8528   : W_f1[h] rows
//  WC0c  [10][52] @ 11128  : W_f0[c] rows
//  W1c   [10][52] @ 11648  : W_f1[c] rows
//  WcommP[50][12] @ 12168  : W_comm rows
#define OFF_WC0  3328
#define OFF_W1S  5928
#define OFF_W1H  8528
#define OFF_WC0c 11128
#define OFF_W1c  11648
#define OFF_WCM  12168
#define NPREP    (OFF_WCM + HID * CLD)   // 12768

__device__ __forceinline__ float fast_tanh(float x) {
  float xc = fminf(15.f, fmaxf(-15.f, x));
  float e  = __expf(2.f * xc);
  return __fdividef(e - 1.f, e + 1.f);
}

__global__ void prep_weights(const float* __restrict__ W_enc,
                             const float* __restrict__ W_f,
                             const float* __restrict__ W_comm,
                             float* __restrict__ ws) {
  int i = blockIdx.x * blockDim.x + threadIdx.x;
  if (i >= NPREP) return;
  if (i < OFF_WCM) {
    int j = i % LD;
    int r = i / LD;
    float v = 0.f;
    if (j < HID) {
      if      (r <  64)                { v = W_enc[r*HID + j]; }
      else if (r < 114) { int k=r-64;    v = W_f[k*HID + j] + W_f[(60+k)*HID + j]; }
      else if (r < 164) { int k=r-114;   v = W_f[(110+60+k)*HID + j]; }
      else if (r < 214) { int k=r-164;   v = W_f[(110+k)*HID + j]; }
      else if (r < 224) { int s=r-214;   v = W_f[(50+s)*HID + j]; }
      else              { int s=r-224;   v = W_f[(110+50+s)*HID + j]; }
    }
    ws[i] = v;
  } else {
    int r = (i - OFF_WCM) / CLD, j = (i - OFF_WCM) % CLD;
    ws[i] = (j < NSYM) ? W_comm[r*NSYM + j] : 0.f;
  }
}

// masked log-softmax argmax step: applies mask to cl[], returns argmax,
// accumulates comm_logp contribution into clp.
__device__ __forceinline__ int comm_pick(float cl[NSYM], float mk, float& clp) {
  #pragma unroll
  for (int s = 0; s < NSYM; s++) cl[s] = (mk == 0.f) ? NEGV : cl[s];
  int w = 0; float best = cl[0];
  #pragma unroll
  for (int s = 1; s < NSYM; s++) { bool b = cl[s] > best; best = b ? cl[s] : best; w = b ? s : w; }
  float se = 0.f;
  #pragma unroll
  for (int s = 0; s < NSYM; s++) se += __expf(cl[s] - best);
  clp += (-__logf(se)) * mk;      // log_softmax at argmax = -log(sum exp(cl-best))
  return w;
}

__global__ __launch_bounds__(TPB, 4) void policy_kernel(
    const float* __restrict__ obs,
    const float* __restrict__ mask,
    const float* __restrict__ b_enc,
    const float* __restrict__ b_f,
    const float* __restrict__ b_comm,
    const float* __restrict__ W_pi,
    const float* __restrict__ b_pi,
    const float* __restrict__ W_v,
    const float* __restrict__ b_v,
    const float* __restrict__ wsP,
    float* __restrict__ out,
    int B)
{
  __shared__ float stash[AG * 51];         // pre1 stash; stride 51 -> 2-way only (free)
  const int t   = threadIdx.x;
  const int be0 = blockIdx.x * BPB;
  const int nbe = min(BPB, B - be0);
  const int nag = nbe * NAGENT;
  const bool act = (t < nag);
  const int bel = t / NAGENT;
  const long long NA = (long long)B * NAGENT;
  const long long g  = (long long)be0 * NAGENT + t;
  const long long gc = act ? g : (NA - 1);
  const int sl = act ? t : 0;
  const int sh = bel * NAGENT;

  const float* WencP = wsP;
  const float* WC0   = wsP + OFF_WC0;
  const float* W1S   = wsP + OFF_W1S;
  const float* W1H   = wsP + OFF_W1H;
  const float* WC0c  = wsP + OFF_WC0c;
  const float* W1c   = wsP + OFF_W1c;
  const float* WCM   = wsP + OFF_WCM;

  const float mk = mask[gc];
  float h[HID];                             // current hidden state, registers only

  // ================= enc: h0 = tanh(obs @ W_enc + b_enc) =================
  {
    float acc[HID];
    #pragma unroll
    for (int j = 0; j < HID; j++) acc[j] = b_enc[j];
    const float4* o4 = (const float4*)(obs + gc * OBS_D);
    #pragma unroll
    for (int half = 0; half < 2; half++) {
      float4 ob[8];                         // 32 obs floats in flight (vmcnt only)
      #pragma unroll
      for (int q = 0; q < 8; q++) ob[q] = o4[half * 8 + q];
      #pragma unroll
      for (int q = 0; q < 8; q++) {
        const float* wr = &WencP[(half * 32 + q * 4) * LD];
        #pragma unroll
        for (int j = 0; j < HID; j++) acc[j] = fmaf(ob[q].x, wr[j], acc[j]);
        #pragma unroll
        for (int j = 0; j < HID; j++) acc[j] = fmaf(ob[q].y, wr[LD + j], acc[j]);
        #pragma unroll
        for (int j = 0; j < HID; j++) acc[j] = fmaf(ob[q].z, wr[2 * LD + j], acc[j]);
        #pragma unroll
        for (int j = 0; j < HID; j++) acc[j] = fmaf(ob[q].w, wr[3 * LD + j], acc[j]);
      }
    }
    #pragma unroll
    for (int j = 0; j < HID; j++) h[j] = fast_tanh(acc[j]);
  }

  // ================= step 0 comm head =================
  float clp = 0.f;
  float c_reg[NSYM];
  int w;
  {
    float cl[NSYM];
    #pragma unroll
    for (int s = 0; s < NSYM; s++) cl[s] = b_comm[s];
    #pragma unroll
    for (int k = 0; k < HID; k++) {
      float x = h[k];
      const float* wr = &WCM[k * CLD];
      #pragma unroll
      for (int s = 0; s < NSYM; s++) cl[s] = fmaf(x, wr[s], cl[s]);
    }
    w = comm_pick(cl, mk, clp);
  }
  #pragma unroll
  for (int s = 0; s < NSYM; s++) {
    unsigned long long b = __ballot(w == s);
    c_reg[s] = ((b >> sh) & 0x3FFULL) ? 1.f : 0.f;
  }

  // ===== pre1 = b_f1 + h0 @ W_f1[skip]  (registers; stash to LDS, then free) =====
  {
    float pre1[HID];
    #pragma unroll
    for (int j = 0; j < HID; j++) pre1[j] = b_f[HID + j];
    #pragma unroll
    for (int k = 0; k < HID; k++) {
      float x = h[k];
      const float* wr = &W1S[k * LD];
      #pragma unroll
      for (int j = 0; j < HID; j++) pre1[j] = fmaf(x, wr[j], pre1[j]);
    }
    if (act) {
      #pragma unroll
      for (int j = 0; j < HID; j++) stash[t * 51 + j] = pre1[j];
    }
  }
  __syncthreads();   // forces the later reload (compiler can't store-forward across it)

  // ===== h1 = tanh(b_f0 + c @ W_f0[c] + h0 @ (W_f0[h]+W_f0[skip])) =====
  {
    float acc[HID];
    #pragma unroll
    for (int j = 0; j < HID; j++) acc[j] = b_f[j];
    #pragma unroll
    for (int s = 0; s < NSYM; s++) {        // c contribution first -> c_reg dies early
      float cv = c_reg[s];
      const float* wr = &WC0c[s * LD];
      #pragma unroll
      for (int j = 0; j < HID; j++) acc[j] = fmaf(cv, wr[j], acc[j]);
    }
    #pragma unroll
    for (int k = 0; k < HID; k++) {
      float x = h[k];
      const float* wr = &WC0[k * LD];
      #pragma unroll
      for (int j = 0; j < HID; j++) acc[j] = fmaf(x, wr[j], acc[j]);
    }
    #pragma unroll
    for (int j = 0; j < HID; j++) h[j] = fast_tanh(acc[j]);   // h0 dead, h = h1
  }

  // ================= step 1 comm head =================
  {
    float cl[NSYM];
    #pragma unroll
    for (int s = 0; s < NSYM; s++) cl[s] = b_comm[s];
    #pragma unroll
    for (int k = 0; k < HID; k++) {
      float x = h[k];
      const float* wr = &WCM[k * CLD];
      #pragma unroll
      for (int s = 0; s < NSYM; s++) cl[s] = fmaf(x, wr[s], cl[s]);
    }
    w = comm_pick(cl, mk, clp);
  }
  #pragma unroll
  for (int s = 0; s < NSYM; s++) {
    unsigned long long b = __ballot(w == s);
    c_reg[s] = ((b >> sh) & 0x3FFULL) ? 1.f : 0.f;   // step-1 c (also the output c)
  }

  // ===== pre2 = stash + c @ W_f1[c] + h1 @ W_f1[h]; h2 = tanh; heads =====
  float l0, l1, bv;
  {
    float pre[HID];
    #pragma unroll
    for (int j = 0; j < HID; j++) pre[j] = stash[sl * 51 + j];
    #pragma unroll
    for (int s = 0; s < NSYM; s++) {
      float cv = c_reg[s];
      const float* wr = &W1c[s * LD];
      #pragma unroll
      for (int j = 0; j < HID; j++) pre[j] = fmaf(cv, wr[j], pre[j]);
    }
    #pragma unroll
    for (int k = 0; k < HID; k++) {
      float x = h[k];
      const float* wr = &W1H[k * LD];
      #pragma unroll
      for (int j = 0; j < HID; j++) pre[j] = fmaf(x, wr[j], pre[j]);
    }
    l0 = b_pi[0]; l1 = b_pi[1]; bv = b_v[0];
    #pragma unroll
    for (int j = 0; j < HID; j++) {
      float hh = fast_tanh(pre[j]);
      l0 = fmaf(hh, W_pi[j * NACT + 0], l0);
      l1 = fmaf(hh, W_pi[j * NACT + 1], l1);
      bv = fmaf(hh, W_v[j], bv);
    }
  }

  if (act) {
    float2* o2 = (float2*)out;
    o2[g] = make_float2((mk == 0.f) ? NEGV : l0, (mk == 0.f) ? NEGV : l1);
    out[NA * 2 + g] = bv * mk;
    out[NA * 3 + g] = clp;
    float2* c2 = (float2*)(out + NA * 4);
    const long long cb = g * (NSYM / 2);
    #pragma unroll
    for (int s = 0; s < NSYM / 2; s++)
      c2[cb + s] = make_float2(c_reg[2 * s], c_reg[2 * s + 1]);
  }
}

extern "C" void kernel_launch(void* const* d_in, const int* in_sizes, int n_in,
                              void* d_out, int out_size, void* d_ws, size_t ws_size,
                              hipStream_t stream) {
  const float* obs    = (const float*)d_in[0];
  const float* mask   = (const float*)d_in[1];
  const float* W_enc  = (const float*)d_in[2];
  const float* b_enc  = (const float*)d_in[3];
  const float* W_f    = (const float*)d_in[4];
  const float* b_f    = (const float*)d_in[5];
  const float* W_comm = (const float*)d_in[6];
  const float* b_comm = (const float*)d_in[7];
  const float* W_pi   = (const float*)d_in[8];
  const float* b_pi   = (const float*)d_in[9];
  const float* W_v    = (const float*)d_in[10];
  const float* b_v    = (const float*)d_in[11];
  float* out = (float*)d_out;
  float* ws  = (float*)d_ws;

  const int B = in_sizes[0] / (NAGENT * OBS_D);

  hipLaunchKernelGGL(prep_weights, dim3((NPREP + 255) / 256), dim3(256), 0, stream,
                     W_enc, W_f, W_comm, ws);

  const int grid = (B + BPB - 1) / BPB;
  hipLaunchKernelGGL(policy_kernel, dim3(grid), dim3(TPB), 0, stream,
                     obs, mask, b_enc, b_f, b_comm, W_pi, b_pi, W_v, b_v,
                     ws, out, B);
}